// Round 2
// baseline (42.759 us; speedup 1.0000x reference)
//
#include <hip/hip_runtime.h>

#define NJ 24
#define EPSF 1e-10f
#define BLK 256
#define GRID_BLOCKS 1024   // 1024 blocks * 4 waves = 4096 waves = 4/SIMD resident;
                           // each thread handles 2 elements -> prefetch overlap

typedef float v4f __attribute__((ext_vector_type(4)));   // native vec for nontemporal store

// Workspace layout (floats):
//   joint j at offset j*20:
//     [0]=theta [1..3]=w(unit) [4..6]=v/theta [7..9]=w x v [10..12]=(w.v)w
//     [13]=wxx [14]=wyy [15]=wzz [16]=wxy [17]=wxz [18]=wyz [19]=pad
//   T_init rows at offset 480: g0[4], g1[4], g2[4]   (R | p)
#define TI_OFF (NJ * 20)
#define WS_FLOATS (TI_OFF + 12)

__global__ void poe_setup(const float* __restrict__ twist,
                          const float* __restrict__ init_p,
                          const float* __restrict__ init_rpy,
                          float* __restrict__ cb)
{
    const int tid = threadIdx.x;
    if (tid < NJ) {
        const int j = tid;
        float wx = twist[j*6+0], wy = twist[j*6+1], wz = twist[j*6+2];
        float vx = twist[j*6+3], vy = twist[j*6+4], vz = twist[j*6+5];
        float theta = sqrtf(wx*wx + wy*wy + wz*wz) + EPSF;
        float inv = 1.0f / theta;
        wx *= inv; wy *= inv; wz *= inv;
        vx *= inv; vy *= inv; vz *= inv;
        float cx = wy*vz - wz*vy;
        float cy = wz*vx - wx*vz;
        float cz = wx*vy - wy*vx;
        float wdv = wx*vx + wy*vy + wz*vz;
        float* c = cb + j*20;
        c[0]=theta; c[1]=wx; c[2]=wy; c[3]=wz;
        c[4]=vx; c[5]=vy; c[6]=vz;
        c[7]=cx; c[8]=cy; c[9]=cz;
        c[10]=wdv*wx; c[11]=wdv*wy; c[12]=wdv*wz;
        c[13]=wx*wx; c[14]=wy*wy; c[15]=wz*wz;
        c[16]=wx*wy; c[17]=wx*wz; c[18]=wy*wz; c[19]=0.f;
    } else if (tid == 32) {
        float r  = init_rpy[0], pt = init_rpy[1], yw = init_rpy[2];
        float cr = cosf(r),  sr = sinf(r);
        float cp = cosf(pt), sp = sinf(pt);
        float cy = cosf(yw), sy = sinf(yw);
        float* t = cb + TI_OFF;
        t[0]=cy*cp; t[1]=cy*sp*sr - sy*cr; t[2]=cy*sp*cr + sy*sr; t[3]=init_p[0];
        t[4]=sy*cp; t[5]=sy*sp*sr + cy*cr; t[6]=sy*sp*cr - cy*sr; t[7]=init_p[1];
        t[8]=-sp;   t[9]=cp*sr;            t[10]=cp*cr;           t[11]=init_p[2];
    }
}

__global__ __launch_bounds__(BLK, 4) void poe_main(
    const float* __restrict__ q,    // (B, 24)
    const float* __restrict__ cb,   // WS_FLOATS constants (uniform -> s_load)
    float* __restrict__ out,        // (B, 4, 4)
    int B)
{
    const int stride = gridDim.x * BLK;
    int b = blockIdx.x * BLK + threadIdx.x;
    if (b >= B) return;

    // Load current element's 24 q values into NAMED registers and pin them
    // (no arrays -> nothing demoted to scratch, rule #20; pins prevent the
    // round-3 pathology of loads re-sunk into the body -> 2.5x over-fetch).
    const float4* qp = reinterpret_cast<const float4*>(q + (size_t)b * NJ);
    float4 qa = qp[0], qb = qp[1], qc = qp[2], qd = qp[3], qe = qp[4], qf = qp[5];
    asm volatile("" : "+v"(qa.x), "+v"(qa.y), "+v"(qa.z), "+v"(qa.w),
                      "+v"(qb.x), "+v"(qb.y), "+v"(qb.z), "+v"(qb.w),
                      "+v"(qc.x), "+v"(qc.y), "+v"(qc.z), "+v"(qc.w));
    asm volatile("" : "+v"(qd.x), "+v"(qd.y), "+v"(qd.z), "+v"(qd.w),
                      "+v"(qe.x), "+v"(qe.y), "+v"(qe.z), "+v"(qe.w),
                      "+v"(qf.x), "+v"(qf.y), "+v"(qf.z), "+v"(qf.w));

    // T_init is loop-invariant uniform (s_load, hoisted once).
    const float* t = cb + TI_OFF;
    const float g00=t[0], g01=t[1], g02=t[2], g03=t[3];
    const float g10=t[4], g11=t[5], g12=t[6], g13=t[7];
    const float g20=t[8], g21=t[9], g22=t[10], g23=t[11];

    while (true) {
        // ---- software prefetch of NEXT element's q, issued BEFORE compute ----
        const int bn = b + stride;
        const int pidx = (bn < B) ? bn : b;     // clamp: last iter re-reads (L2 hit)
        const float4* np = reinterpret_cast<const float4*>(q + (size_t)pidx * NJ);
        float4 f0 = np[0], f1 = np[1], f2 = np[2], f3 = np[3], f4 = np[4], f5 = np[5];
        asm volatile("" : "+v"(f0.x), "+v"(f0.y), "+v"(f0.z), "+v"(f0.w),
                          "+v"(f1.x), "+v"(f1.y), "+v"(f1.z), "+v"(f1.w),
                          "+v"(f2.x), "+v"(f2.y), "+v"(f2.z), "+v"(f2.w));
        asm volatile("" : "+v"(f3.x), "+v"(f3.y), "+v"(f3.z), "+v"(f3.w),
                          "+v"(f4.x), "+v"(f4.y), "+v"(f4.z), "+v"(f4.w),
                          "+v"(f5.x), "+v"(f5.y), "+v"(f5.z), "+v"(f5.w));

        // ---- compute current element (HBM latency of f* hides under this) ----
        float R00=1.f, R01=0.f, R02=0.f;
        float R10=0.f, R11=1.f, R12=0.f;
        float R20=0.f, R21=0.f, R22=1.f;
        float px=0.f, py=0.f, pz=0.f;

        // One fully-unrolled joint step. Constants come from uniform scalar
        // loads (compile-time offsets off cb). Every FMA has <=1 SGPR operand.
#define JSTEP(J, QJ) { \
    const float* c = cb + (J)*20; \
    const float qt = (QJ) * c[0]; \
    const float s  = __sinf(qt); \
    const float cc = __cosf(qt); \
    const float oc = 1.0f - cc; \
    const float a  = qt - s; \
    const float t1 = s * c[3], t2 = s * c[2], t3 = s * c[1]; \
    const float A00 = fmaf(oc, c[13],  cc); \
    const float A11 = fmaf(oc, c[14],  cc); \
    const float A22 = fmaf(oc, c[15],  cc); \
    const float A01 = fmaf(oc, c[16], -t1); \
    const float A10 = fmaf(oc, c[16],  t1); \
    const float A02 = fmaf(oc, c[17],  t2); \
    const float A20 = fmaf(oc, c[17], -t2); \
    const float A12 = fmaf(oc, c[18], -t3); \
    const float A21 = fmaf(oc, c[18],  t3); \
    const float pjx = fmaf(s, c[4], fmaf(oc, c[7], a * c[10])); \
    const float pjy = fmaf(s, c[5], fmaf(oc, c[8], a * c[11])); \
    const float pjz = fmaf(s, c[6], fmaf(oc, c[9], a * c[12])); \
    px = fmaf(R00, pjx, fmaf(R01, pjy, fmaf(R02, pjz, px))); \
    py = fmaf(R10, pjx, fmaf(R11, pjy, fmaf(R12, pjz, py))); \
    pz = fmaf(R20, pjx, fmaf(R21, pjy, fmaf(R22, pjz, pz))); \
    const float N00 = fmaf(R00, A00, fmaf(R01, A10, R02 * A20)); \
    const float N01 = fmaf(R00, A01, fmaf(R01, A11, R02 * A21)); \
    const float N02 = fmaf(R00, A02, fmaf(R01, A12, R02 * A22)); \
    const float N10 = fmaf(R10, A00, fmaf(R11, A10, R12 * A20)); \
    const float N11 = fmaf(R10, A01, fmaf(R11, A11, R12 * A21)); \
    const float N12 = fmaf(R10, A02, fmaf(R11, A12, R12 * A22)); \
    const float N20 = fmaf(R20, A00, fmaf(R21, A10, R22 * A20)); \
    const float N21 = fmaf(R20, A01, fmaf(R21, A11, R22 * A21)); \
    const float N22 = fmaf(R20, A02, fmaf(R21, A12, R22 * A22)); \
    R00=N00; R01=N01; R02=N02; \
    R10=N10; R11=N11; R12=N12; \
    R20=N20; R21=N21; R22=N22; \
}

        JSTEP(0,  qa.x) JSTEP(1,  qa.y) JSTEP(2,  qa.z) JSTEP(3,  qa.w)
        JSTEP(4,  qb.x) JSTEP(5,  qb.y) JSTEP(6,  qb.z) JSTEP(7,  qb.w)
        JSTEP(8,  qc.x) JSTEP(9,  qc.y) JSTEP(10, qc.z) JSTEP(11, qc.w)
        JSTEP(12, qd.x) JSTEP(13, qd.y) JSTEP(14, qd.z) JSTEP(15, qd.w)
        JSTEP(16, qe.x) JSTEP(17, qe.y) JSTEP(18, qe.z) JSTEP(19, qe.w)
        JSTEP(20, qf.x) JSTEP(21, qf.y) JSTEP(22, qf.z) JSTEP(23, qf.w)
#undef JSTEP

        // out = carry @ T_init   (uniform scalar operands)
        const float O00 = fmaf(R00, g00, fmaf(R01, g10, R02 * g20));
        const float O01 = fmaf(R00, g01, fmaf(R01, g11, R02 * g21));
        const float O02 = fmaf(R00, g02, fmaf(R01, g12, R02 * g22));
        const float Opx = fmaf(R00, g03, fmaf(R01, g13, fmaf(R02, g23, px)));

        const float O10 = fmaf(R10, g00, fmaf(R11, g10, R12 * g20));
        const float O11 = fmaf(R10, g01, fmaf(R11, g11, R12 * g21));
        const float O12 = fmaf(R10, g02, fmaf(R11, g12, R12 * g22));
        const float Opy = fmaf(R10, g03, fmaf(R11, g13, fmaf(R12, g23, py)));

        const float O20 = fmaf(R20, g00, fmaf(R21, g10, R22 * g20));
        const float O21 = fmaf(R20, g01, fmaf(R21, g11, R22 * g21));
        const float O22 = fmaf(R20, g02, fmaf(R21, g12, R22 * g22));
        const float Opz = fmaf(R20, g03, fmaf(R21, g13, fmaf(R22, g23, pz)));

        // Streaming output: nontemporal 16-B stores keep L2 for the q stream.
        v4f* o4 = reinterpret_cast<v4f*>(out + (size_t)b * 16);
        v4f r0 = { O00, O01, O02, Opx };
        v4f r1 = { O10, O11, O12, Opy };
        v4f r2 = { O20, O21, O22, Opz };
        v4f r3 = { 0.f, 0.f, 0.f, 1.f };
        __builtin_nontemporal_store(r0, &o4[0]);
        __builtin_nontemporal_store(r1, &o4[1]);
        __builtin_nontemporal_store(r2, &o4[2]);
        __builtin_nontemporal_store(r3, &o4[3]);

        if (bn >= B) break;
        b = bn;
        qa = f0; qb = f1; qc = f2; qd = f3; qe = f4; qf = f5;
    }
}

extern "C" void kernel_launch(void* const* d_in, const int* in_sizes, int n_in,
                              void* d_out, int out_size, void* d_ws, size_t ws_size,
                              hipStream_t stream) {
    const float* q        = (const float*)d_in[0];
    const float* twist    = (const float*)d_in[1];
    const float* init_p   = (const float*)d_in[2];
    const float* init_rpy = (const float*)d_in[3];
    float* out            = (float*)d_out;
    float* cb             = (float*)d_ws;   // needs WS_FLOATS*4 = 1968 bytes

    const int B = in_sizes[0] / NJ;
    const int need = (B + BLK - 1) / BLK;
    const int blocks = need < GRID_BLOCKS ? need : GRID_BLOCKS;

    poe_setup<<<1, 64, 0, stream>>>(twist, init_p, init_rpy, cb);
    poe_main<<<blocks, BLK, 0, stream>>>(q, cb, out, B);
}

// Round 3
// 42.377 us; speedup vs baseline: 1.0090x; 1.0090x over previous
//
#include <hip/hip_runtime.h>

#define NJ 24
#define EPSF 1e-10f
#define BLK 256

// Each thread processes exactly 2 elements (b0, b0+stride), software-pipelined:
//   load q(b0) -> wait -> issue q(b1) loads -> sched_barrier (pin issue, NO wait)
//   -> compute+store b0 (hides b1's HBM latency) -> compute+store b1.
// grid = ceil(B/2/BLK) = 1024 blocks @ B=524288 -> 4 blocks/CU, 16 waves/CU.

// Workspace layout (floats):
//   joint j at offset j*20:
//     [0]=theta [1..3]=w(unit) [4..6]=v/theta [7..9]=w x v [10..12]=(w.v)w
//     [13]=wxx [14]=wyy [15]=wzz [16]=wxy [17]=wxz [18]=wyz [19]=pad
//   T_init rows at offset 480: g0[4], g1[4], g2[4]   (R | p)
#define TI_OFF (NJ * 20)
#define WS_FLOATS (TI_OFF + 12)

__global__ void poe_setup(const float* __restrict__ twist,
                          const float* __restrict__ init_p,
                          const float* __restrict__ init_rpy,
                          float* __restrict__ cb)
{
    const int tid = threadIdx.x;
    if (tid < NJ) {
        const int j = tid;
        float wx = twist[j*6+0], wy = twist[j*6+1], wz = twist[j*6+2];
        float vx = twist[j*6+3], vy = twist[j*6+4], vz = twist[j*6+5];
        float theta = sqrtf(wx*wx + wy*wy + wz*wz) + EPSF;
        float inv = 1.0f / theta;
        wx *= inv; wy *= inv; wz *= inv;
        vx *= inv; vy *= inv; vz *= inv;
        float cx = wy*vz - wz*vy;
        float cy = wz*vx - wx*vz;
        float cz = wx*vy - wy*vx;
        float wdv = wx*vx + wy*vy + wz*vz;
        float* c = cb + j*20;
        c[0]=theta; c[1]=wx; c[2]=wy; c[3]=wz;
        c[4]=vx; c[5]=vy; c[6]=vz;
        c[7]=cx; c[8]=cy; c[9]=cz;
        c[10]=wdv*wx; c[11]=wdv*wy; c[12]=wdv*wz;
        c[13]=wx*wx; c[14]=wy*wy; c[15]=wz*wz;
        c[16]=wx*wy; c[17]=wx*wz; c[18]=wy*wz; c[19]=0.f;
    } else if (tid == 32) {
        float r  = init_rpy[0], pt = init_rpy[1], yw = init_rpy[2];
        float cr = cosf(r),  sr = sinf(r);
        float cp = cosf(pt), sp = sinf(pt);
        float cy = cosf(yw), sy = sinf(yw);
        float* t = cb + TI_OFF;
        t[0]=cy*cp; t[1]=cy*sp*sr - sy*cr; t[2]=cy*sp*cr + sy*sr; t[3]=init_p[0];
        t[4]=sy*cp; t[5]=sy*sp*sr + cy*cr; t[6]=sy*sp*cr - cy*sr; t[7]=init_p[1];
        t[8]=-sp;   t[9]=cp*sr;            t[10]=cp*cr;           t[11]=init_p[2];
    }
}

// One fully-unrolled joint step. Constants come from uniform scalar loads
// (compile-time offsets off cb). Every FMA has <=1 SGPR operand.
#define JSTEP(J, QJ) { \
    const float* c = cb + (J)*20; \
    const float qt = (QJ) * c[0]; \
    const float s  = __sinf(qt); \
    const float cc = __cosf(qt); \
    const float oc = 1.0f - cc; \
    const float a  = qt - s; \
    const float t1 = s * c[3], t2 = s * c[2], t3 = s * c[1]; \
    const float A00 = fmaf(oc, c[13],  cc); \
    const float A11 = fmaf(oc, c[14],  cc); \
    const float A22 = fmaf(oc, c[15],  cc); \
    const float A01 = fmaf(oc, c[16], -t1); \
    const float A10 = fmaf(oc, c[16],  t1); \
    const float A02 = fmaf(oc, c[17],  t2); \
    const float A20 = fmaf(oc, c[17], -t2); \
    const float A12 = fmaf(oc, c[18], -t3); \
    const float A21 = fmaf(oc, c[18],  t3); \
    const float pjx = fmaf(s, c[4], fmaf(oc, c[7], a * c[10])); \
    const float pjy = fmaf(s, c[5], fmaf(oc, c[8], a * c[11])); \
    const float pjz = fmaf(s, c[6], fmaf(oc, c[9], a * c[12])); \
    px = fmaf(R00, pjx, fmaf(R01, pjy, fmaf(R02, pjz, px))); \
    py = fmaf(R10, pjx, fmaf(R11, pjy, fmaf(R12, pjz, py))); \
    pz = fmaf(R20, pjx, fmaf(R21, pjy, fmaf(R22, pjz, pz))); \
    const float N00 = fmaf(R00, A00, fmaf(R01, A10, R02 * A20)); \
    const float N01 = fmaf(R00, A01, fmaf(R01, A11, R02 * A21)); \
    const float N02 = fmaf(R00, A02, fmaf(R01, A12, R02 * A22)); \
    const float N10 = fmaf(R10, A00, fmaf(R11, A10, R12 * A20)); \
    const float N11 = fmaf(R10, A01, fmaf(R11, A11, R12 * A21)); \
    const float N12 = fmaf(R10, A02, fmaf(R11, A12, R12 * A22)); \
    const float N20 = fmaf(R20, A00, fmaf(R21, A10, R22 * A20)); \
    const float N21 = fmaf(R20, A01, fmaf(R21, A11, R22 * A21)); \
    const float N22 = fmaf(R20, A02, fmaf(R21, A12, R22 * A22)); \
    R00=N00; R01=N01; R02=N02; \
    R10=N10; R11=N11; R12=N12; \
    R20=N20; R21=N21; R22=N22; \
}

// Full chain for one element given 24 q values in named regs, then store.
#define ELEMENT_BODY(BIDX) { \
    float R00=1.f, R01=0.f, R02=0.f; \
    float R10=0.f, R11=1.f, R12=0.f; \
    float R20=0.f, R21=0.f, R22=1.f; \
    float px=0.f, py=0.f, pz=0.f; \
    JSTEP(0,  qa.x) JSTEP(1,  qa.y) JSTEP(2,  qa.z) JSTEP(3,  qa.w) \
    JSTEP(4,  qb.x) JSTEP(5,  qb.y) JSTEP(6,  qb.z) JSTEP(7,  qb.w) \
    JSTEP(8,  qc.x) JSTEP(9,  qc.y) JSTEP(10, qc.z) JSTEP(11, qc.w) \
    JSTEP(12, qd.x) JSTEP(13, qd.y) JSTEP(14, qd.z) JSTEP(15, qd.w) \
    JSTEP(16, qe.x) JSTEP(17, qe.y) JSTEP(18, qe.z) JSTEP(19, qe.w) \
    JSTEP(20, qf.x) JSTEP(21, qf.y) JSTEP(22, qf.z) JSTEP(23, qf.w) \
    const float O00 = fmaf(R00, g00, fmaf(R01, g10, R02 * g20)); \
    const float O01 = fmaf(R00, g01, fmaf(R01, g11, R02 * g21)); \
    const float O02 = fmaf(R00, g02, fmaf(R01, g12, R02 * g22)); \
    const float Opx = fmaf(R00, g03, fmaf(R01, g13, fmaf(R02, g23, px))); \
    const float O10 = fmaf(R10, g00, fmaf(R11, g10, R12 * g20)); \
    const float O11 = fmaf(R10, g01, fmaf(R11, g11, R12 * g21)); \
    const float O12 = fmaf(R10, g02, fmaf(R11, g12, R12 * g22)); \
    const float Opy = fmaf(R10, g03, fmaf(R11, g13, fmaf(R12, g23, py))); \
    const float O20 = fmaf(R20, g00, fmaf(R21, g10, R22 * g20)); \
    const float O21 = fmaf(R20, g01, fmaf(R21, g11, R22 * g21)); \
    const float O22 = fmaf(R20, g02, fmaf(R21, g12, R22 * g22)); \
    const float Opz = fmaf(R20, g03, fmaf(R21, g13, fmaf(R22, g23, pz))); \
    float4* o4 = reinterpret_cast<float4*>(out + (size_t)(BIDX) * 16); \
    o4[0] = make_float4(O00, O01, O02, Opx); \
    o4[1] = make_float4(O10, O11, O12, Opy); \
    o4[2] = make_float4(O20, O21, O22, Opz); \
    o4[3] = make_float4(0.f, 0.f, 0.f, 1.f); \
}

__global__ __launch_bounds__(BLK, 4) void poe_main(
    const float* __restrict__ q,    // (B, 24)
    const float* __restrict__ cb,   // WS_FLOATS constants (uniform -> s_load)
    float* __restrict__ out,        // (B, 4, 4)
    int B)
{
    const int stride = gridDim.x * BLK;
    const int b0 = blockIdx.x * BLK + threadIdx.x;
    if (b0 >= B) return;
    const int b1 = b0 + stride;
    const bool has2 = (b1 < B);

    // --- element 0 loads: pin forces vmcnt wait HERE (only these 6 loads
    // are outstanding), keeping the known-good anti-over-fetch behavior.
    const float4* qp = reinterpret_cast<const float4*>(q + (size_t)b0 * NJ);
    float4 qa = qp[0], qb = qp[1], qc = qp[2], qd = qp[3], qe = qp[4], qf = qp[5];
    asm volatile("" : "+v"(qa.x), "+v"(qa.y), "+v"(qa.z), "+v"(qa.w),
                      "+v"(qb.x), "+v"(qb.y), "+v"(qb.z), "+v"(qb.w),
                      "+v"(qc.x), "+v"(qc.y), "+v"(qc.z), "+v"(qc.w));
    asm volatile("" : "+v"(qd.x), "+v"(qd.y), "+v"(qd.z), "+v"(qd.w),
                      "+v"(qe.x), "+v"(qe.y), "+v"(qe.z), "+v"(qe.w),
                      "+v"(qf.x), "+v"(qf.y), "+v"(qf.z), "+v"(qf.w));

    // --- element 1 loads: ISSUE now, do NOT wait. sched_barrier(0) pins the
    // issue position (prevents sinking) without inserting any s_waitcnt —
    // the wait lands naturally at first use, after element 0's body.
    const int pidx = has2 ? b1 : b0;   // tail threads re-read b0 (L2 hit, body skipped)
    const float4* np = reinterpret_cast<const float4*>(q + (size_t)pidx * NJ);
    float4 f0 = np[0], f1 = np[1], f2 = np[2], f3 = np[3], f4 = np[4], f5 = np[5];
    __builtin_amdgcn_sched_barrier(0);

    // T_init is uniform (s_load, hoisted once).
    const float* t = cb + TI_OFF;
    const float g00=t[0], g01=t[1], g02=t[2], g03=t[3];
    const float g10=t[4], g11=t[5], g12=t[6], g13=t[7];
    const float g20=t[8], g21=t[9], g22=t[10], g23=t[11];

    // --- element 0: compute + store (f* HBM latency hides under this) ---
    ELEMENT_BODY(b0)

    // --- element 1 ---
    if (has2) {
        qa = f0; qb = f1; qc = f2; qd = f3; qe = f4; qf = f5;
        ELEMENT_BODY(b1)
    }
}

#undef ELEMENT_BODY
#undef JSTEP

extern "C" void kernel_launch(void* const* d_in, const int* in_sizes, int n_in,
                              void* d_out, int out_size, void* d_ws, size_t ws_size,
                              hipStream_t stream) {
    const float* q        = (const float*)d_in[0];
    const float* twist    = (const float*)d_in[1];
    const float* init_p   = (const float*)d_in[2];
    const float* init_rpy = (const float*)d_in[3];
    float* out            = (float*)d_out;
    float* cb             = (float*)d_ws;   // needs WS_FLOATS*4 = 1968 bytes

    const int B = in_sizes[0] / NJ;
    const int threads_needed = (B + 1) / 2;              // 2 elements per thread
    const int blocks = (threads_needed + BLK - 1) / BLK; // = 1024 @ B=524288

    poe_setup<<<1, 64, 0, stream>>>(twist, init_p, init_rpy, cb);
    poe_main<<<blocks, BLK, 0, stream>>>(q, cb, out, B);
}

// Round 4
// 40.416 us; speedup vs baseline: 1.0580x; 1.0485x over previous
//
#include <hip/hip_runtime.h>

#define NJ 24
#define EPSF 1e-10f
#define BLK 256

// Workspace layout (floats):
//   joint j at offset j*20:
//     [0]=theta [1..3]=w(unit) [4..6]=v/theta [7..9]=w x v [10..12]=(w.v)w
//     [13]=wxx [14]=wyy [15]=wzz [16]=wxy [17]=wxz [18]=wyz [19]=pad
//   T_init rows at offset 480: g0[4], g1[4], g2[4]   (R | p)
#define TI_OFF (NJ * 20)
#define WS_FLOATS (TI_OFF + 12)

__global__ void poe_setup(const float* __restrict__ twist,
                          const float* __restrict__ init_p,
                          const float* __restrict__ init_rpy,
                          float* __restrict__ cb)
{
    const int tid = threadIdx.x;
    if (tid < NJ) {
        const int j = tid;
        float wx = twist[j*6+0], wy = twist[j*6+1], wz = twist[j*6+2];
        float vx = twist[j*6+3], vy = twist[j*6+4], vz = twist[j*6+5];
        float theta = sqrtf(wx*wx + wy*wy + wz*wz) + EPSF;
        float inv = 1.0f / theta;
        wx *= inv; wy *= inv; wz *= inv;
        vx *= inv; vy *= inv; vz *= inv;
        float cx = wy*vz - wz*vy;
        float cy = wz*vx - wx*vz;
        float cz = wx*vy - wy*vx;
        float wdv = wx*vx + wy*vy + wz*vz;
        float* c = cb + j*20;
        c[0]=theta; c[1]=wx; c[2]=wy; c[3]=wz;
        c[4]=vx; c[5]=vy; c[6]=vz;
        c[7]=cx; c[8]=cy; c[9]=cz;
        c[10]=wdv*wx; c[11]=wdv*wy; c[12]=wdv*wz;
        c[13]=wx*wx; c[14]=wy*wy; c[15]=wz*wz;
        c[16]=wx*wy; c[17]=wx*wz; c[18]=wy*wz; c[19]=0.f;
    } else if (tid == 32) {
        float r  = init_rpy[0], pt = init_rpy[1], yw = init_rpy[2];
        float cr = cosf(r),  sr = sinf(r);
        float cp = cosf(pt), sp = sinf(pt);
        float cy = cosf(yw), sy = sinf(yw);
        float* t = cb + TI_OFF;
        t[0]=cy*cp; t[1]=cy*sp*sr - sy*cr; t[2]=cy*sp*cr + sy*sr; t[3]=init_p[0];
        t[4]=sy*cp; t[5]=sy*sp*sr + cy*cr; t[6]=sy*sp*cr - cy*sr; t[7]=init_p[1];
        t[8]=-sp;   t[9]=cp*sr;            t[10]=cp*cr;           t[11]=init_p[2];
    }
}

// One fully-unrolled joint step. Constants come from uniform scalar loads
// (compile-time offsets off cb). Every FMA has <=1 SGPR operand.
#define JSTEP(J, QJ) { \
    const float* c = cb + (J)*20; \
    const float qt = (QJ) * c[0]; \
    const float s  = __sinf(qt); \
    const float cc = __cosf(qt); \
    const float oc = 1.0f - cc; \
    const float a  = qt - s; \
    const float t1 = s * c[3], t2 = s * c[2], t3 = s * c[1]; \
    const float A00 = fmaf(oc, c[13],  cc); \
    const float A11 = fmaf(oc, c[14],  cc); \
    const float A22 = fmaf(oc, c[15],  cc); \
    const float A01 = fmaf(oc, c[16], -t1); \
    const float A10 = fmaf(oc, c[16],  t1); \
    const float A02 = fmaf(oc, c[17],  t2); \
    const float A20 = fmaf(oc, c[17], -t2); \
    const float A12 = fmaf(oc, c[18], -t3); \
    const float A21 = fmaf(oc, c[18],  t3); \
    const float pjx = fmaf(s, c[4], fmaf(oc, c[7], a * c[10])); \
    const float pjy = fmaf(s, c[5], fmaf(oc, c[8], a * c[11])); \
    const float pjz = fmaf(s, c[6], fmaf(oc, c[9], a * c[12])); \
    px = fmaf(R00, pjx, fmaf(R01, pjy, fmaf(R02, pjz, px))); \
    py = fmaf(R10, pjx, fmaf(R11, pjy, fmaf(R12, pjz, py))); \
    pz = fmaf(R20, pjx, fmaf(R21, pjy, fmaf(R22, pjz, pz))); \
    const float N00 = fmaf(R00, A00, fmaf(R01, A10, R02 * A20)); \
    const float N01 = fmaf(R00, A01, fmaf(R01, A11, R02 * A21)); \
    const float N02 = fmaf(R00, A02, fmaf(R01, A12, R02 * A22)); \
    const float N10 = fmaf(R10, A00, fmaf(R11, A10, R12 * A20)); \
    const float N11 = fmaf(R10, A01, fmaf(R11, A11, R12 * A21)); \
    const float N12 = fmaf(R10, A02, fmaf(R11, A12, R12 * A22)); \
    const float N20 = fmaf(R20, A00, fmaf(R21, A10, R22 * A20)); \
    const float N21 = fmaf(R20, A01, fmaf(R21, A11, R22 * A21)); \
    const float N22 = fmaf(R20, A02, fmaf(R21, A12, R22 * A22)); \
    R00=N00; R01=N01; R02=N02; \
    R10=N10; R11=N11; R12=N12; \
    R20=N20; R21=N21; R22=N22; \
}

__global__ __launch_bounds__(BLK) void poe_main(
    const float* __restrict__ q,    // (B, 24)
    const float* __restrict__ cb,   // WS_FLOATS constants (uniform -> s_load)
    float* __restrict__ out,        // (B, 4, 4)
    int B)
{
    const int w = threadIdx.x >> 6;        // wave id in block (0..3)
    const int l = threadIdx.x & 63;        // lane
    const int ebase = blockIdx.x * BLK;    // block's first element
    const int b = ebase + threadIdx.x;     // this thread's element

    // Wave-private transpose-staging buffer.
    // Per wave: 64 elems * 28-float padded rows = 448 float4 (7168 B).
    // Block: 4 * 448 * 16 B = 28672 B  -> 5 blocks/CU (staggered generations).
    // Padded stride 28 floats => ds_read_b128 bank starts {0,4,...,28}: 8-way
    // = the wave64 b128 floor (1 KB through 128 B/cyc of banks). Benign.
    __shared__ float4 sbuf[4 * 448];

    float4 qa, qb, qc, qd, qe, qf;

    if (ebase + BLK <= B) {
        // ---- fast path: coalesced wave load + LDS transpose ----
        // Wave's q region: 64 elems * 24 floats = 384 float4 chunks, contiguous.
        const float4* gq = reinterpret_cast<const float4*>(q) +
                           (size_t)(ebase + (w << 6)) * 6;
        float4* wbuf = sbuf + w * 448;
        #pragma unroll
        for (int r = 0; r < 6; ++r) {
            const int c = (r << 6) + l;          // chunk index 0..383
            const float4 f = gq[c];              // lane-contiguous: 16 lines/instr
            const int e = (c * 10923) >> 16;     // c / 6  (exact for c < 2978)
            const int j = c - e * 6;             // c % 6
            wbuf[e * 7 + j] = f;                 // padded row e, chunk j
        }
        // Thread (elem = lane l of wave) reads its 24 floats back.
        // Compiler inserts lgkmcnt before first use (may-alias on sbuf);
        // wave-synchronous, no __syncthreads needed (region is wave-private).
        const float4* tb = wbuf + l * 7;
        qa = tb[0]; qb = tb[1]; qc = tb[2]; qd = tb[3]; qe = tb[4]; qf = tb[5];
    } else {
        // ---- tail path: direct (possibly partial) loads ----
        if (b >= B) return;
        const float4* qp = reinterpret_cast<const float4*>(q + (size_t)b * NJ);
        qa = qp[0]; qb = qp[1]; qc = qp[2]; qd = qp[3]; qe = qp[4]; qf = qp[5];
    }

    // T_init is uniform (s_load, hoisted once).
    const float* t = cb + TI_OFF;
    const float g00=t[0], g01=t[1], g02=t[2], g03=t[3];
    const float g10=t[4], g11=t[5], g12=t[6], g13=t[7];
    const float g20=t[8], g21=t[9], g22=t[10], g23=t[11];

    float R00=1.f, R01=0.f, R02=0.f;
    float R10=0.f, R11=1.f, R12=0.f;
    float R20=0.f, R21=0.f, R22=1.f;
    float px=0.f, py=0.f, pz=0.f;

    JSTEP(0,  qa.x) JSTEP(1,  qa.y) JSTEP(2,  qa.z) JSTEP(3,  qa.w)
    JSTEP(4,  qb.x) JSTEP(5,  qb.y) JSTEP(6,  qb.z) JSTEP(7,  qb.w)
    JSTEP(8,  qc.x) JSTEP(9,  qc.y) JSTEP(10, qc.z) JSTEP(11, qc.w)
    JSTEP(12, qd.x) JSTEP(13, qd.y) JSTEP(14, qd.z) JSTEP(15, qd.w)
    JSTEP(16, qe.x) JSTEP(17, qe.y) JSTEP(18, qe.z) JSTEP(19, qe.w)
    JSTEP(20, qf.x) JSTEP(21, qf.y) JSTEP(22, qf.z) JSTEP(23, qf.w)

    // out = carry @ T_init   (uniform scalar operands)
    const float O00 = fmaf(R00, g00, fmaf(R01, g10, R02 * g20));
    const float O01 = fmaf(R00, g01, fmaf(R01, g11, R02 * g21));
    const float O02 = fmaf(R00, g02, fmaf(R01, g12, R02 * g22));
    const float Opx = fmaf(R00, g03, fmaf(R01, g13, fmaf(R02, g23, px)));

    const float O10 = fmaf(R10, g00, fmaf(R11, g10, R12 * g20));
    const float O11 = fmaf(R10, g01, fmaf(R11, g11, R12 * g21));
    const float O12 = fmaf(R10, g02, fmaf(R11, g12, R12 * g22));
    const float Opy = fmaf(R10, g03, fmaf(R11, g13, fmaf(R12, g23, py)));

    const float O20 = fmaf(R20, g00, fmaf(R21, g10, R22 * g20));
    const float O21 = fmaf(R20, g01, fmaf(R21, g11, R22 * g21));
    const float O22 = fmaf(R20, g02, fmaf(R21, g12, R22 * g22));
    const float Opz = fmaf(R20, g03, fmaf(R21, g13, fmaf(R22, g23, pz)));

    float4* o4 = reinterpret_cast<float4*>(out + (size_t)b * 16);
    o4[0] = make_float4(O00, O01, O02, Opx);
    o4[1] = make_float4(O10, O11, O12, Opy);
    o4[2] = make_float4(O20, O21, O22, Opz);
    o4[3] = make_float4(0.f, 0.f, 0.f, 1.f);
}

#undef JSTEP

extern "C" void kernel_launch(void* const* d_in, const int* in_sizes, int n_in,
                              void* d_out, int out_size, void* d_ws, size_t ws_size,
                              hipStream_t stream) {
    const float* q        = (const float*)d_in[0];
    const float* twist    = (const float*)d_in[1];
    const float* init_p   = (const float*)d_in[2];
    const float* init_rpy = (const float*)d_in[3];
    float* out            = (float*)d_out;
    float* cb             = (float*)d_ws;   // needs WS_FLOATS*4 = 1968 bytes

    const int B = in_sizes[0] / NJ;
    const int blocks = (B + BLK - 1) / BLK;   // 1 element per thread

    poe_setup<<<1, 64, 0, stream>>>(twist, init_p, init_rpy, cb);
    poe_main<<<blocks, BLK, 0, stream>>>(q, cb, out, B);
}

// Round 5
// 38.306 us; speedup vs baseline: 1.1162x; 1.0551x over previous
//
#include <hip/hip_runtime.h>

#define NJ 24
#define EPSF 1e-10f
#define BLK 256
#define FLAG_MAGIC 0x7E57C0DEu

// Workspace layout (floats):
//   joint j at offset j*20:
//     [0]=theta [1..3]=w(unit) [4..6]=v/theta [7..9]=w x v [10..12]=(w.v)w
//     [13]=wxx [14]=wyy [15]=wzz [16]=wxy [17]=wxz [18]=wyz [19]=pad
//   T_init rows at offset 480: g0[4], g1[4], g2[4]   (R | p)
//   flag (uint) at float index 496 (its own 64B line; never touched via cb/ws)
#define TI_OFF (NJ * 20)
#define WS_FLOATS (TI_OFF + 12)
#define FLAG_IDX 496

// One fully-unrolled joint step. Constants come from uniform scalar loads
// (compile-time offsets off cb). Every FMA has <=1 SGPR operand.
#define JSTEP(J, QJ) { \
    const float* c = cb + (J)*20; \
    const float qt = (QJ) * c[0]; \
    const float s  = __sinf(qt); \
    const float cc = __cosf(qt); \
    const float oc = 1.0f - cc; \
    const float a  = qt - s; \
    const float t1 = s * c[3], t2 = s * c[2], t3 = s * c[1]; \
    const float A00 = fmaf(oc, c[13],  cc); \
    const float A11 = fmaf(oc, c[14],  cc); \
    const float A22 = fmaf(oc, c[15],  cc); \
    const float A01 = fmaf(oc, c[16], -t1); \
    const float A10 = fmaf(oc, c[16],  t1); \
    const float A02 = fmaf(oc, c[17],  t2); \
    const float A20 = fmaf(oc, c[17], -t2); \
    const float A12 = fmaf(oc, c[18], -t3); \
    const float A21 = fmaf(oc, c[18],  t3); \
    const float pjx = fmaf(s, c[4], fmaf(oc, c[7], a * c[10])); \
    const float pjy = fmaf(s, c[5], fmaf(oc, c[8], a * c[11])); \
    const float pjz = fmaf(s, c[6], fmaf(oc, c[9], a * c[12])); \
    px = fmaf(R00, pjx, fmaf(R01, pjy, fmaf(R02, pjz, px))); \
    py = fmaf(R10, pjx, fmaf(R11, pjy, fmaf(R12, pjz, py))); \
    pz = fmaf(R20, pjx, fmaf(R21, pjy, fmaf(R22, pjz, pz))); \
    const float N00 = fmaf(R00, A00, fmaf(R01, A10, R02 * A20)); \
    const float N01 = fmaf(R00, A01, fmaf(R01, A11, R02 * A21)); \
    const float N02 = fmaf(R00, A02, fmaf(R01, A12, R02 * A22)); \
    const float N10 = fmaf(R10, A00, fmaf(R11, A10, R12 * A20)); \
    const float N11 = fmaf(R10, A01, fmaf(R11, A11, R12 * A21)); \
    const float N12 = fmaf(R10, A02, fmaf(R11, A12, R12 * A22)); \
    const float N20 = fmaf(R20, A00, fmaf(R21, A10, R22 * A20)); \
    const float N21 = fmaf(R20, A01, fmaf(R21, A11, R22 * A21)); \
    const float N22 = fmaf(R20, A02, fmaf(R21, A12, R22 * A22)); \
    R00=N00; R01=N01; R02=N02; \
    R10=N10; R11=N11; R12=N12; \
    R20=N20; R21=N21; R22=N22; \
}

__global__ __launch_bounds__(BLK) void poe_fused(
    const float* __restrict__ q,        // (B, 24)
    const float* __restrict__ twist,    // (24, 6)
    const float* __restrict__ init_p,   // (3)
    const float* __restrict__ init_rpy, // (3)
    float* __restrict__ ws,             // write path for constants (block 0 only)
    const float* __restrict__ cb,       // read path (same memory as ws; ordering
                                        // enforced by the asm memory barrier below)
    unsigned int* __restrict__ flag,    // d_ws + FLAG_IDX floats
    float* __restrict__ out,            // (B, 4, 4)
    int B)
{
    const int tid = threadIdx.x;
    const int b = blockIdx.x * BLK + tid;
    const bool valid = (b < B);

    float4 qa, qb, qc, qd, qe, qf;

    if (blockIdx.x == 0) {
        // ---- setup duty: compute per-joint constants + T_init into ws ----
        if (tid < NJ) {
            const int j = tid;
            float wx = twist[j*6+0], wy = twist[j*6+1], wz = twist[j*6+2];
            float vx = twist[j*6+3], vy = twist[j*6+4], vz = twist[j*6+5];
            float theta = sqrtf(wx*wx + wy*wy + wz*wz) + EPSF;
            float inv = 1.0f / theta;
            wx *= inv; wy *= inv; wz *= inv;
            vx *= inv; vy *= inv; vz *= inv;
            float cx = wy*vz - wz*vy;
            float cy = wz*vx - wx*vz;
            float cz = wx*vy - wy*vx;
            float wdv = wx*vx + wy*vy + wz*vz;
            float* c = ws + j*20;
            c[0]=theta; c[1]=wx; c[2]=wy; c[3]=wz;
            c[4]=vx; c[5]=vy; c[6]=vz;
            c[7]=cx; c[8]=cy; c[9]=cz;
            c[10]=wdv*wx; c[11]=wdv*wy; c[12]=wdv*wz;
            c[13]=wx*wx; c[14]=wy*wy; c[15]=wz*wz;
            c[16]=wx*wy; c[17]=wx*wz; c[18]=wy*wz; c[19]=0.f;
        } else if (tid == 32) {
            float r  = init_rpy[0], pt = init_rpy[1], yw = init_rpy[2];
            float cr = cosf(r),  sr = sinf(r);
            float cp = cosf(pt), sp = sinf(pt);
            float cy = cosf(yw), sy = sinf(yw);
            float* t = ws + TI_OFF;
            t[0]=cy*cp; t[1]=cy*sp*sr - sy*cr; t[2]=cy*sp*cr + sy*sr; t[3]=init_p[0];
            t[4]=sy*cp; t[5]=sy*sp*sr + cy*cr; t[6]=sy*sp*cr - cy*sr; t[7]=init_p[1];
            t[8]=-sp;   t[9]=cp*sr;            t[10]=cp*cr;           t[11]=init_p[2];
        }
        __syncthreads();                 // all block-0 writes done
        if (tid == 0) {
            // agent-scope release: L2 writeback so remote XCDs see fresh cb
            __builtin_amdgcn_fence(__ATOMIC_RELEASE, "agent");
            __hip_atomic_store(flag, FLAG_MAGIC, __ATOMIC_RELAXED,
                               __HIP_MEMORY_SCOPE_AGENT);
        }
        if (valid) {                     // block 0 loads q after setup
            const float4* qp = reinterpret_cast<const float4*>(q + (size_t)b * NJ);
            qa = qp[0]; qb = qp[1]; qc = qp[2]; qd = qp[3]; qe = qp[4]; qf = qp[5];
        }
    } else {
        // issue q loads BEFORE the spin: HBM latency hides under the wait
        if (valid) {
            const float4* qp = reinterpret_cast<const float4*>(q + (size_t)b * NJ);
            qa = qp[0]; qb = qp[1]; qc = qp[2]; qd = qp[3]; qe = qp[4]; qf = qp[5];
        }
        if (tid == 0) {
            while (__hip_atomic_load(flag, __ATOMIC_RELAXED,
                                     __HIP_MEMORY_SCOPE_AGENT) != FLAG_MAGIC)
                __builtin_amdgcn_s_sleep(8);
            // agent-scope acquire: invalidates this CU's L1 + this XCD's L2,
            // so a re-poisoned workspace can never serve stale cb lines.
            __builtin_amdgcn_fence(__ATOMIC_ACQUIRE, "agent");
        }
        __syncthreads();
    }

    // Compiler barrier: no cb load may be hoisted above the flag handshake
    // (ws/cb restrict-alias the same memory; this is the ordering fence).
    asm volatile("" ::: "memory");

    if (!valid) return;

    // Pin the 24 q values in NAMED registers (rule #20 / anti-over-fetch,
    // identical to the 35.9us baseline).
    asm volatile("" : "+v"(qa.x), "+v"(qa.y), "+v"(qa.z), "+v"(qa.w),
                      "+v"(qb.x), "+v"(qb.y), "+v"(qb.z), "+v"(qb.w),
                      "+v"(qc.x), "+v"(qc.y), "+v"(qc.z), "+v"(qc.w));
    asm volatile("" : "+v"(qd.x), "+v"(qd.y), "+v"(qd.z), "+v"(qd.w),
                      "+v"(qe.x), "+v"(qe.y), "+v"(qe.z), "+v"(qe.w),
                      "+v"(qf.x), "+v"(qf.y), "+v"(qf.z), "+v"(qf.w));

    float R00=1.f, R01=0.f, R02=0.f;
    float R10=0.f, R11=1.f, R12=0.f;
    float R20=0.f, R21=0.f, R22=1.f;
    float px=0.f, py=0.f, pz=0.f;

    JSTEP(0,  qa.x) JSTEP(1,  qa.y) JSTEP(2,  qa.z) JSTEP(3,  qa.w)
    JSTEP(4,  qb.x) JSTEP(5,  qb.y) JSTEP(6,  qb.z) JSTEP(7,  qb.w)
    JSTEP(8,  qc.x) JSTEP(9,  qc.y) JSTEP(10, qc.z) JSTEP(11, qc.w)
    JSTEP(12, qd.x) JSTEP(13, qd.y) JSTEP(14, qd.z) JSTEP(15, qd.w)
    JSTEP(16, qe.x) JSTEP(17, qe.y) JSTEP(18, qe.z) JSTEP(19, qe.w)
    JSTEP(20, qf.x) JSTEP(21, qf.y) JSTEP(22, qf.z) JSTEP(23, qf.w)

    // out = carry @ T_init   (uniform scalar reads)
    const float* t = cb + TI_OFF;
    const float g00=t[0], g01=t[1], g02=t[2], g03=t[3];
    const float g10=t[4], g11=t[5], g12=t[6], g13=t[7];
    const float g20=t[8], g21=t[9], g22=t[10], g23=t[11];

    const float O00 = fmaf(R00, g00, fmaf(R01, g10, R02 * g20));
    const float O01 = fmaf(R00, g01, fmaf(R01, g11, R02 * g21));
    const float O02 = fmaf(R00, g02, fmaf(R01, g12, R02 * g22));
    const float Opx = fmaf(R00, g03, fmaf(R01, g13, fmaf(R02, g23, px)));

    const float O10 = fmaf(R10, g00, fmaf(R11, g10, R12 * g20));
    const float O11 = fmaf(R10, g01, fmaf(R11, g11, R12 * g21));
    const float O12 = fmaf(R10, g02, fmaf(R11, g12, R12 * g22));
    const float Opy = fmaf(R10, g03, fmaf(R11, g13, fmaf(R12, g23, py)));

    const float O20 = fmaf(R20, g00, fmaf(R21, g10, R22 * g20));
    const float O21 = fmaf(R20, g01, fmaf(R21, g11, R22 * g21));
    const float O22 = fmaf(R20, g02, fmaf(R21, g12, R22 * g22));
    const float Opz = fmaf(R20, g03, fmaf(R21, g13, fmaf(R22, g23, pz)));

    float4* o4 = reinterpret_cast<float4*>(out + (size_t)b * 16);
    o4[0] = make_float4(O00, O01, O02, Opx);
    o4[1] = make_float4(O10, O11, O12, Opy);
    o4[2] = make_float4(O20, O21, O22, Opz);
    o4[3] = make_float4(0.f, 0.f, 0.f, 1.f);
}

#undef JSTEP

extern "C" void kernel_launch(void* const* d_in, const int* in_sizes, int n_in,
                              void* d_out, int out_size, void* d_ws, size_t ws_size,
                              hipStream_t stream) {
    const float* q        = (const float*)d_in[0];
    const float* twist    = (const float*)d_in[1];
    const float* init_p   = (const float*)d_in[2];
    const float* init_rpy = (const float*)d_in[3];
    float* out            = (float*)d_out;
    float* ws             = (float*)d_ws;                 // needs (496+1)*4 = 1988+ bytes
    unsigned int* flag    = (unsigned int*)(ws + FLAG_IDX);

    const int B = in_sizes[0] / NJ;
    const int blocks = (B + BLK - 1) / BLK;               // 2048 @ B=524288

    // Single kernel: block 0 computes constants, 2047 blocks flag-spin (~1us)
    // with their q loads already in flight. Removes the setup-kernel launch +
    // graph dependency gap (~2.5-3us of the 35.9us total).
    poe_fused<<<blocks, BLK, 0, stream>>>(q, twist, init_p, init_rpy,
                                          ws, ws, flag, out, B);
}

// Round 6
// 36.277 us; speedup vs baseline: 1.1787x; 1.0559x over previous
//
#include <hip/hip_runtime.h>

#define NJ 24
#define EPSF 1e-10f
#define BLK 256

typedef float f2 __attribute__((ext_vector_type(2)));

// Workspace layout (floats):
//   joint j at offset j*20:
//     [0]=theta [1..3]=w(unit) [4..6]=v/theta [7..9]=w x v [10..12]=(w.v)w
//     [13]=wxx [14]=wyy [15]=wzz [16]=wxy [17]=wxz [18]=wyz [19]=pad
//   T_init rows at offset 480: g0[4], g1[4], g2[4]   (R | p)
#define TI_OFF (NJ * 20)
#define WS_FLOATS (TI_OFF + 12)

__global__ void poe_setup(const float* __restrict__ twist,
                          const float* __restrict__ init_p,
                          const float* __restrict__ init_rpy,
                          float* __restrict__ cb)
{
    const int tid = threadIdx.x;
    if (tid < NJ) {
        const int j = tid;
        float wx = twist[j*6+0], wy = twist[j*6+1], wz = twist[j*6+2];
        float vx = twist[j*6+3], vy = twist[j*6+4], vz = twist[j*6+5];
        float theta = sqrtf(wx*wx + wy*wy + wz*wz) + EPSF;
        float inv = 1.0f / theta;
        wx *= inv; wy *= inv; wz *= inv;
        vx *= inv; vy *= inv; vz *= inv;
        float cx = wy*vz - wz*vy;
        float cy = wz*vx - wx*vz;
        float cz = wx*vy - wy*vx;
        float wdv = wx*vx + wy*vy + wz*vz;
        float* c = cb + j*20;
        c[0]=theta; c[1]=wx; c[2]=wy; c[3]=wz;
        c[4]=vx; c[5]=vy; c[6]=vz;
        c[7]=cx; c[8]=cy; c[9]=cz;
        c[10]=wdv*wx; c[11]=wdv*wy; c[12]=wdv*wz;
        c[13]=wx*wx; c[14]=wy*wy; c[15]=wz*wz;
        c[16]=wx*wy; c[17]=wx*wz; c[18]=wy*wz; c[19]=0.f;
    } else if (tid == 32) {
        float r  = init_rpy[0], pt = init_rpy[1], yw = init_rpy[2];
        float cr = cosf(r),  sr = sinf(r);
        float cp = cosf(pt), sp = sinf(pt);
        float cy = cosf(yw), sy = sinf(yw);
        float* t = cb + TI_OFF;
        t[0]=cy*cp; t[1]=cy*sp*sr - sy*cr; t[2]=cy*sp*cr + sy*sr; t[3]=init_p[0];
        t[4]=sy*cp; t[5]=sy*sp*sr + cy*cr; t[6]=sy*sp*cr - cy*sr; t[7]=init_p[1];
        t[8]=-sp;   t[9]=cp*sr;            t[10]=cp*cr;           t[11]=init_p[2];
    }
}

// State per row i:  RA_i = (R_i0, R_i1)   RB_i = (R_i2, p_i)
// Per joint, build column pairs:
//   P0=(A00,A01) P1=(A10,A11) P2=(A20,A21)          (A = cc*I + s*W + oc*w w^T)
//   P3=(A02,pjx) P4=(A12,pjy) P5=(A22,pjz)          (pj = s*v + oc*(wxv) + a*(w.v)w)
// Row update (21 packed FMAs replace 39 scalar):
//   RA_i' = Ri0*P0 + Ri1*P1 + Ri2*P2
//   RB_i' = Ri0*P3 + Ri1*P4 + Ri2*P5 + (0, p_i)
// Associativity matches the scalar baseline exactly (same rounding).
#define JSTEP(J, QJ) { \
    const float* c = cb + (J)*20; \
    const float qt = (QJ) * c[0]; \
    const float s  = __sinf(qt); \
    const float cc = __cosf(qt); \
    const float oc = 1.0f - cc; \
    const float a  = qt - s; \
    const float t1 = s * c[3], t2 = s * c[2], t3 = s * c[1]; \
    f2 P0, P1, P2, P3, P4, P5; \
    P0.x = fmaf(oc, c[13],  cc); \
    P0.y = fmaf(oc, c[16], -t1); \
    P1.x = fmaf(oc, c[16],  t1); \
    P1.y = fmaf(oc, c[14],  cc); \
    P2.x = fmaf(oc, c[17], -t2); \
    P2.y = fmaf(oc, c[18],  t3); \
    P3.x = fmaf(oc, c[17],  t2); \
    P3.y = fmaf(s, c[4], fmaf(oc, c[7], a * c[10])); \
    P4.x = fmaf(oc, c[18], -t3); \
    P4.y = fmaf(s, c[5], fmaf(oc, c[8], a * c[11])); \
    P5.x = fmaf(oc, c[15],  cc); \
    P5.y = fmaf(s, c[6], fmaf(oc, c[9], a * c[12])); \
    { \
        const f2 b0 = RA0.xx, b1 = RA0.yy, b2 = RB0.xx; \
        f2 na = __builtin_elementwise_fma(b2, P2, __builtin_elementwise_fma(b1, P1, b0 * P0)); \
        f2 nb = RB0 * K01; \
        nb = __builtin_elementwise_fma(b2, P5, __builtin_elementwise_fma(b1, P4, __builtin_elementwise_fma(b0, P3, nb))); \
        RA0 = na; RB0 = nb; \
    } \
    { \
        const f2 b0 = RA1.xx, b1 = RA1.yy, b2 = RB1.xx; \
        f2 na = __builtin_elementwise_fma(b2, P2, __builtin_elementwise_fma(b1, P1, b0 * P0)); \
        f2 nb = RB1 * K01; \
        nb = __builtin_elementwise_fma(b2, P5, __builtin_elementwise_fma(b1, P4, __builtin_elementwise_fma(b0, P3, nb))); \
        RA1 = na; RB1 = nb; \
    } \
    { \
        const f2 b0 = RA2.xx, b1 = RA2.yy, b2 = RB2.xx; \
        f2 na = __builtin_elementwise_fma(b2, P2, __builtin_elementwise_fma(b1, P1, b0 * P0)); \
        f2 nb = RB2 * K01; \
        nb = __builtin_elementwise_fma(b2, P5, __builtin_elementwise_fma(b1, P4, __builtin_elementwise_fma(b0, P3, nb))); \
        RA2 = na; RB2 = nb; \
    } \
}

__global__ __launch_bounds__(BLK) void poe_main(
    const float* __restrict__ q,    // (B, 24)
    const float* __restrict__ cb,   // WS_FLOATS constants (uniform -> s_load)
    float* __restrict__ out,        // (B, 4, 4)
    int B)
{
    const int b = blockIdx.x * BLK + threadIdx.x;
    if (b >= B) return;

    const float4* qp = reinterpret_cast<const float4*>(q + (size_t)b * NJ);

    // All 24 q values in NAMED registers, pinned (rule #20 / anti-over-fetch).
    float4 qa = qp[0], qb = qp[1], qc = qp[2], qd = qp[3], qe = qp[4], qf = qp[5];
    asm volatile("" : "+v"(qa.x), "+v"(qa.y), "+v"(qa.z), "+v"(qa.w),
                      "+v"(qb.x), "+v"(qb.y), "+v"(qb.z), "+v"(qb.w),
                      "+v"(qc.x), "+v"(qc.y), "+v"(qc.z), "+v"(qc.w));
    asm volatile("" : "+v"(qd.x), "+v"(qd.y), "+v"(qd.z), "+v"(qd.w),
                      "+v"(qe.x), "+v"(qe.y), "+v"(qe.z), "+v"(qe.w),
                      "+v"(qf.x), "+v"(qf.y), "+v"(qf.z), "+v"(qf.w));

    const f2 K01 = {0.0f, 1.0f};

    // R = I, p = 0
    f2 RA0 = {1.f, 0.f}, RB0 = {0.f, 0.f};
    f2 RA1 = {0.f, 1.f}, RB1 = {0.f, 0.f};
    f2 RA2 = {0.f, 0.f}, RB2 = {1.f, 0.f};

    JSTEP(0,  qa.x) JSTEP(1,  qa.y) JSTEP(2,  qa.z) JSTEP(3,  qa.w)
    JSTEP(4,  qb.x) JSTEP(5,  qb.y) JSTEP(6,  qb.z) JSTEP(7,  qb.w)
    JSTEP(8,  qc.x) JSTEP(9,  qc.y) JSTEP(10, qc.z) JSTEP(11, qc.w)
    JSTEP(12, qd.x) JSTEP(13, qd.y) JSTEP(14, qd.z) JSTEP(15, qd.w)
    JSTEP(16, qe.x) JSTEP(17, qe.y) JSTEP(18, qe.z) JSTEP(19, qe.w)
    JSTEP(20, qf.x) JSTEP(21, qf.y) JSTEP(22, qf.z) JSTEP(23, qf.w)

    // Unpack state
    const float R00 = RA0.x, R01 = RA0.y, R02 = RB0.x, px = RB0.y;
    const float R10 = RA1.x, R11 = RA1.y, R12 = RB1.x, py = RB1.y;
    const float R20 = RA2.x, R21 = RA2.y, R22 = RB2.x, pz = RB2.y;

    // out = carry @ T_init   (uniform scalar reads)
    const float* t = cb + TI_OFF;
    const float g00=t[0], g01=t[1], g02=t[2], g03=t[3];
    const float g10=t[4], g11=t[5], g12=t[6], g13=t[7];
    const float g20=t[8], g21=t[9], g22=t[10], g23=t[11];

    const float O00 = fmaf(R00, g00, fmaf(R01, g10, R02 * g20));
    const float O01 = fmaf(R00, g01, fmaf(R01, g11, R02 * g21));
    const float O02 = fmaf(R00, g02, fmaf(R01, g12, R02 * g22));
    const float Opx = fmaf(R00, g03, fmaf(R01, g13, fmaf(R02, g23, px)));

    const float O10 = fmaf(R10, g00, fmaf(R11, g10, R12 * g20));
    const float O11 = fmaf(R10, g01, fmaf(R11, g11, R12 * g21));
    const float O12 = fmaf(R10, g02, fmaf(R11, g12, R12 * g22));
    const float Opy = fmaf(R10, g03, fmaf(R11, g13, fmaf(R12, g23, py)));

    const float O20 = fmaf(R20, g00, fmaf(R21, g10, R22 * g20));
    const float O21 = fmaf(R20, g01, fmaf(R21, g11, R22 * g21));
    const float O22 = fmaf(R20, g02, fmaf(R21, g12, R22 * g22));
    const float Opz = fmaf(R20, g03, fmaf(R21, g13, fmaf(R22, g23, pz)));

    float4* o4 = reinterpret_cast<float4*>(out + (size_t)b * 16);
    o4[0] = make_float4(O00, O01, O02, Opx);
    o4[1] = make_float4(O10, O11, O12, Opy);
    o4[2] = make_float4(O20, O21, O22, Opz);
    o4[3] = make_float4(0.f, 0.f, 0.f, 1.f);
}

#undef JSTEP

extern "C" void kernel_launch(void* const* d_in, const int* in_sizes, int n_in,
                              void* d_out, int out_size, void* d_ws, size_t ws_size,
                              hipStream_t stream) {
    const float* q        = (const float*)d_in[0];
    const float* twist    = (const float*)d_in[1];
    const float* init_p   = (const float*)d_in[2];
    const float* init_rpy = (const float*)d_in[3];
    float* out            = (float*)d_out;
    float* cb             = (float*)d_ws;   // needs WS_FLOATS*4 = 1968 bytes

    const int B = in_sizes[0] / NJ;
    const int blocks = (B + BLK - 1) / BLK;

    poe_setup<<<1, 64, 0, stream>>>(twist, init_p, init_rpy, cb);
    poe_main<<<blocks, BLK, 0, stream>>>(q, cb, out, B);
}

// Round 7
// 35.685 us; speedup vs baseline: 1.1982x; 1.0166x over previous
//
#include <hip/hip_runtime.h>

#define NJ 24
#define EPSF 1e-10f
#define BLK 256

// Workspace layout (floats):
//   joint j at offset j*20:
//     [0]=theta [1..3]=w(unit) [4..6]=v/theta [7..9]=w x v [10..12]=(w.v)w
//     [13]=wxx [14]=wyy [15]=wzz [16]=wxy [17]=wxz [18]=wyz [19]=pad
//   T_init rows at offset 480: g0[4], g1[4], g2[4]   (R | p)
#define TI_OFF (NJ * 20)
#define WS_FLOATS (TI_OFF + 12)

__global__ void poe_setup(const float* __restrict__ twist,
                          const float* __restrict__ init_p,
                          const float* __restrict__ init_rpy,
                          float* __restrict__ cb)
{
    const int tid = threadIdx.x;
    if (tid < NJ) {
        const int j = tid;
        float wx = twist[j*6+0], wy = twist[j*6+1], wz = twist[j*6+2];
        float vx = twist[j*6+3], vy = twist[j*6+4], vz = twist[j*6+5];
        float theta = sqrtf(wx*wx + wy*wy + wz*wz) + EPSF;
        float inv = 1.0f / theta;
        wx *= inv; wy *= inv; wz *= inv;
        vx *= inv; vy *= inv; vz *= inv;
        float cx = wy*vz - wz*vy;
        float cy = wz*vx - wx*vz;
        float cz = wx*vy - wy*vx;
        float wdv = wx*vx + wy*vy + wz*vz;
        float* c = cb + j*20;
        c[0]=theta; c[1]=wx; c[2]=wy; c[3]=wz;
        c[4]=vx; c[5]=vy; c[6]=vz;
        c[7]=cx; c[8]=cy; c[9]=cz;
        c[10]=wdv*wx; c[11]=wdv*wy; c[12]=wdv*wz;
        c[13]=wx*wx; c[14]=wy*wy; c[15]=wz*wz;
        c[16]=wx*wy; c[17]=wx*wz; c[18]=wy*wz; c[19]=0.f;
    } else if (tid == 32) {
        float r  = init_rpy[0], pt = init_rpy[1], yw = init_rpy[2];
        float cr = cosf(r),  sr = sinf(r);
        float cp = cosf(pt), sp = sinf(pt);
        float cy = cosf(yw), sy = sinf(yw);
        float* t = cb + TI_OFF;
        t[0]=cy*cp; t[1]=cy*sp*sr - sy*cr; t[2]=cy*sp*cr + sy*sr; t[3]=init_p[0];
        t[4]=sy*cp; t[5]=sy*sp*sr + cy*cr; t[6]=sy*sp*cr - cy*sr; t[7]=init_p[1];
        t[8]=-sp;   t[9]=cp*sr;            t[10]=cp*cr;           t[11]=init_p[2];
    }
}

// ---- double-banked scalar-constant software pipeline ----
// JLOAD issues the 19 uniform s_loads for joint J into bank P (named scalar
// variables -> SGPRs). Placed one joint AHEAD of use so the lgkmcnt(0) drain
// (SMEM returns out-of-order) is covered by ~128 cycles of the previous
// joint's VALU work instead of stalling the whole SIMD.
#define JLOAD(P, J) { \
    const float* c = cb + (J)*20; \
    P##0 = c[0];  P##1 = c[1];  P##2 = c[2];  P##3 = c[3];  P##4 = c[4]; \
    P##5 = c[5];  P##6 = c[6];  P##7 = c[7];  P##8 = c[8];  P##9 = c[9]; \
    P##10 = c[10]; P##11 = c[11]; P##12 = c[12]; P##13 = c[13]; P##14 = c[14]; \
    P##15 = c[15]; P##16 = c[16]; P##17 = c[17]; P##18 = c[18]; \
}

// One joint step using bank P (same arithmetic/rounding as the baseline).
#define JCOMP(P, QJ) { \
    const float qt = (QJ) * P##0; \
    const float s  = __sinf(qt); \
    const float cc = __cosf(qt); \
    const float oc = 1.0f - cc; \
    const float a  = qt - s; \
    const float t1 = s * P##3, t2 = s * P##2, t3 = s * P##1; \
    const float A00 = fmaf(oc, P##13,  cc); \
    const float A11 = fmaf(oc, P##14,  cc); \
    const float A22 = fmaf(oc, P##15,  cc); \
    const float A01 = fmaf(oc, P##16, -t1); \
    const float A10 = fmaf(oc, P##16,  t1); \
    const float A02 = fmaf(oc, P##17,  t2); \
    const float A20 = fmaf(oc, P##17, -t2); \
    const float A12 = fmaf(oc, P##18, -t3); \
    const float A21 = fmaf(oc, P##18,  t3); \
    const float pjx = fmaf(s, P##4, fmaf(oc, P##7, a * P##10)); \
    const float pjy = fmaf(s, P##5, fmaf(oc, P##8, a * P##11)); \
    const float pjz = fmaf(s, P##6, fmaf(oc, P##9, a * P##12)); \
    px = fmaf(R00, pjx, fmaf(R01, pjy, fmaf(R02, pjz, px))); \
    py = fmaf(R10, pjx, fmaf(R11, pjy, fmaf(R12, pjz, py))); \
    pz = fmaf(R20, pjx, fmaf(R21, pjy, fmaf(R22, pjz, pz))); \
    const float N00 = fmaf(R00, A00, fmaf(R01, A10, R02 * A20)); \
    const float N01 = fmaf(R00, A01, fmaf(R01, A11, R02 * A21)); \
    const float N02 = fmaf(R00, A02, fmaf(R01, A12, R02 * A22)); \
    const float N10 = fmaf(R10, A00, fmaf(R11, A10, R12 * A20)); \
    const float N11 = fmaf(R10, A01, fmaf(R11, A11, R12 * A21)); \
    const float N12 = fmaf(R10, A02, fmaf(R11, A12, R12 * A22)); \
    const float N20 = fmaf(R20, A00, fmaf(R21, A10, R22 * A20)); \
    const float N21 = fmaf(R20, A01, fmaf(R21, A11, R22 * A21)); \
    const float N22 = fmaf(R20, A02, fmaf(R21, A12, R22 * A22)); \
    R00=N00; R01=N01; R02=N02; \
    R10=N10; R11=N11; R12=N12; \
    R20=N20; R21=N21; R22=N22; \
}

__global__ __launch_bounds__(BLK) void poe_main(
    const float* __restrict__ q,    // (B, 24)
    const float* __restrict__ cb,   // WS_FLOATS constants (uniform -> s_load)
    float* __restrict__ out,        // (B, 4, 4)
    int B)
{
    const int b = blockIdx.x * BLK + threadIdx.x;
    if (b >= B) return;

    const float4* qp = reinterpret_cast<const float4*>(q + (size_t)b * NJ);

    // All 24 q values in NAMED registers, pinned (rule #20 / anti-over-fetch).
    float4 qa = qp[0], qb = qp[1], qc = qp[2], qd = qp[3], qe = qp[4], qf = qp[5];
    asm volatile("" : "+v"(qa.x), "+v"(qa.y), "+v"(qa.z), "+v"(qa.w),
                      "+v"(qb.x), "+v"(qb.y), "+v"(qb.z), "+v"(qb.w),
                      "+v"(qc.x), "+v"(qc.y), "+v"(qc.z), "+v"(qc.w));
    asm volatile("" : "+v"(qd.x), "+v"(qd.y), "+v"(qd.z), "+v"(qd.w),
                      "+v"(qe.x), "+v"(qe.y), "+v"(qe.z), "+v"(qe.w),
                      "+v"(qf.x), "+v"(qf.y), "+v"(qf.z), "+v"(qf.w));

    float R00=1.f, R01=0.f, R02=0.f;
    float R10=0.f, R11=1.f, R12=0.f;
    float R20=0.f, R21=0.f, R22=1.f;
    float px=0.f, py=0.f, pz=0.f;

    // Two constant banks (19 scalars each -> SGPRs).
    float ka0,ka1,ka2,ka3,ka4,ka5,ka6,ka7,ka8,ka9,
          ka10,ka11,ka12,ka13,ka14,ka15,ka16,ka17,ka18;
    float kb0,kb1,kb2,kb3,kb4,kb5,kb6,kb7,kb8,kb9,
          kb10,kb11,kb12,kb13,kb14,kb15,kb16,kb17,kb18;

    // Prologue: joints 0 and 1 in flight before any compute.
    JLOAD(ka, 0) JLOAD(kb, 1)

    // Steady state: compute joint j from its bank, immediately refill that
    // bank with joint j+2 (wait for j+2 lands after joint j+1's compute).
    JCOMP(ka, qa.x) JLOAD(ka, 2)
    JCOMP(kb, qa.y) JLOAD(kb, 3)
    JCOMP(ka, qa.z) JLOAD(ka, 4)
    JCOMP(kb, qa.w) JLOAD(kb, 5)
    JCOMP(ka, qb.x) JLOAD(ka, 6)
    JCOMP(kb, qb.y) JLOAD(kb, 7)
    JCOMP(ka, qb.z) JLOAD(ka, 8)
    JCOMP(kb, qb.w) JLOAD(kb, 9)
    JCOMP(ka, qc.x) JLOAD(ka, 10)
    JCOMP(kb, qc.y) JLOAD(kb, 11)
    JCOMP(ka, qc.z) JLOAD(ka, 12)
    JCOMP(kb, qc.w) JLOAD(kb, 13)
    JCOMP(ka, qd.x) JLOAD(ka, 14)
    JCOMP(kb, qd.y) JLOAD(kb, 15)
    JCOMP(ka, qd.z) JLOAD(ka, 16)
    JCOMP(kb, qd.w) JLOAD(kb, 17)
    JCOMP(ka, qe.x) JLOAD(ka, 18)
    JCOMP(kb, qe.y) JLOAD(kb, 19)
    JCOMP(ka, qe.z) JLOAD(ka, 20)
    JCOMP(kb, qe.w) JLOAD(kb, 21)
    JCOMP(ka, qf.x) JLOAD(ka, 22)
    JCOMP(kb, qf.y) JLOAD(kb, 23)
    JCOMP(ka, qf.z)
    JCOMP(kb, qf.w)

    // out = carry @ T_init   (uniform scalar reads)
    const float* t = cb + TI_OFF;
    const float g00=t[0], g01=t[1], g02=t[2], g03=t[3];
    const float g10=t[4], g11=t[5], g12=t[6], g13=t[7];
    const float g20=t[8], g21=t[9], g22=t[10], g23=t[11];

    const float O00 = fmaf(R00, g00, fmaf(R01, g10, R02 * g20));
    const float O01 = fmaf(R00, g01, fmaf(R01, g11, R02 * g21));
    const float O02 = fmaf(R00, g02, fmaf(R01, g12, R02 * g22));
    const float Opx = fmaf(R00, g03, fmaf(R01, g13, fmaf(R02, g23, px)));

    const float O10 = fmaf(R10, g00, fmaf(R11, g10, R12 * g20));
    const float O11 = fmaf(R10, g01, fmaf(R11, g11, R12 * g21));
    const float O12 = fmaf(R10, g02, fmaf(R11, g12, R12 * g22));
    const float Opy = fmaf(R10, g03, fmaf(R11, g13, fmaf(R12, g23, py)));

    const float O20 = fmaf(R20, g00, fmaf(R21, g10, R22 * g20));
    const float O21 = fmaf(R20, g01, fmaf(R21, g11, R22 * g21));
    const float O22 = fmaf(R20, g02, fmaf(R21, g12, R22 * g22));
    const float Opz = fmaf(R20, g03, fmaf(R21, g13, fmaf(R22, g23, pz)));

    float4* o4 = reinterpret_cast<float4*>(out + (size_t)b * 16);
    o4[0] = make_float4(O00, O01, O02, Opx);
    o4[1] = make_float4(O10, O11, O12, Opy);
    o4[2] = make_float4(O20, O21, O22, Opz);
    o4[3] = make_float4(0.f, 0.f, 0.f, 1.f);
}

#undef JLOAD
#undef JCOMP

extern "C" void kernel_launch(void* const* d_in, const int* in_sizes, int n_in,
                              void* d_out, int out_size, void* d_ws, size_t ws_size,
                              hipStream_t stream) {
    const float* q        = (const float*)d_in[0];
    const float* twist    = (const float*)d_in[1];
    const float* init_p   = (const float*)d_in[2];
    const float* init_rpy = (const float*)d_in[3];
    float* out            = (float*)d_out;
    float* cb             = (float*)d_ws;   // needs WS_FLOATS*4 = 1968 bytes

    const int B = in_sizes[0] / NJ;
    const int blocks = (B + BLK - 1) / BLK;

    poe_setup<<<1, 64, 0, stream>>>(twist, init_p, init_rpy, cb);
    poe_main<<<blocks, BLK, 0, stream>>>(q, cb, out, B);
}